// Round 7
// baseline (125.078 us; speedup 1.0000x reference)
//
#include <hip/hip_runtime.h>
#include <hip/hip_bf16.h>
#include <hip/hip_fp16.h>

#if defined(__has_builtin)
#  if __has_builtin(__builtin_amdgcn_mfma_f32_16x16x16bf16_1k) && \
      __has_builtin(__builtin_amdgcn_mfma_f32_16x16x16f16)
#    define USE_K16 1
#  else
#    define USE_K16 0
#  endif
#else
#  define USE_K16 0
#endif

#if defined(__has_builtin)
#  if __has_builtin(__builtin_amdgcn_exp2f)
#    define EXP2(x) __builtin_amdgcn_exp2f(x)
#  else
#    define EXP2(x) exp2f(x)
#  endif
#else
#  define EXP2(x) exp2f(x)
#endif

typedef _Float16 half8_t  __attribute__((ext_vector_type(8)));
typedef _Float16 half4_t  __attribute__((ext_vector_type(4)));
typedef short    short8_t __attribute__((ext_vector_type(8)));
typedef short    short4_t __attribute__((ext_vector_type(4)));
typedef float    f32x4    __attribute__((ext_vector_type(4)));

#define LOG2E 1.44269504088896f

// ---------------------------------------------------------------------------
// Kernel 1 (v5): f = x@Wf+bf (f16), g = (x@Wg+bg)*log2e (f16, prescaled so
// attn can use raw v_exp_f32), v = x@Wh+bh (bf16).
//  USE_K16:  vT3[b][n>>4][ch][n&15] -> 16x16x16 A-frag = 8B contiguous
//  fallback: vT2[b][n>>5][(n>>3)&3][ch][n&7] (R5 frag tiling)
// ---------------------------------------------------------------------------
__global__ __launch_bounds__(256) void prep_kernel(
    const float* __restrict__ x,
    const float* __restrict__ Wf, const float* __restrict__ bf,
    const float* __restrict__ Wg, const float* __restrict__ bg,
    const float* __restrict__ Wh, const float* __restrict__ bh,
    _Float16* __restrict__ fh, _Float16* __restrict__ gh,
    unsigned short* __restrict__ vT)
{
  __shared__ float XsT[64 * 33];   // [c][pos], pad 33 -> conflict-free
  __shared__ float Wall[64 * 80];  // [c][ch]; ch 0-7 = Wf, 8-15 = Wg*log2e, 16-79 = Wh
  __shared__ float ball[80];
  const int t  = threadIdx.x;
  const int p0 = blockIdx.x * 32;  // flat position base (B*N)

  for (int i = t; i < 512; i += 256) {
    Wall[(i >> 3) * 80 + (i & 7)]     = Wf[i];
    Wall[(i >> 3) * 80 + 8 + (i & 7)] = Wg[i] * LOG2E;
  }
  for (int i = t; i < 4096; i += 256)
    Wall[(i >> 6) * 80 + 16 + (i & 63)] = Wh[i];
  if (t < 80) ball[t] = (t < 8) ? bf[t] : (t < 16) ? bg[t - 8] * LOG2E : bh[t - 16];

  const float4* xs = (const float4*)(x + (size_t)p0 * 64);
#pragma unroll
  for (int i = 0; i < 2; i++) {
    int idx = t + i * 256;          // 512 float4 = 32 rows x 16
    int row = idx >> 4, c4 = idx & 15;
    float4 v = xs[idx];
    XsT[(c4 * 4 + 0) * 33 + row] = v.x;
    XsT[(c4 * 4 + 1) * 33 + row] = v.y;
    XsT[(c4 * 4 + 2) * 33 + row] = v.z;
    XsT[(c4 * 4 + 3) * 33 + row] = v.w;
  }
  __syncthreads();

  const int pos = t & 31;
  const int g   = t >> 5;          // 0..7
  const int cb  = g * 10;          // channel base (even -> float2-aligned)

  float acc[10];
#pragma unroll
  for (int j = 0; j < 10; j++) acc[j] = ball[cb + j];

  for (int c = 0; c < 64; c++) {
    float xv = XsT[c * 33 + pos];
    const float2* wr = (const float2*)&Wall[c * 80 + cb];
#pragma unroll
    for (int k = 0; k < 5; k++) {
      float2 w2 = wr[k];
      acc[2 * k]     += xv * w2.x;
      acc[2 * k + 1] += xv * w2.y;
    }
  }

  const size_t pg = (size_t)p0 + pos;
  const int b = (int)(pg >> 12);
  const int n = (int)(pg & 4095);
#if USE_K16
  const size_t vidx = ((size_t)b * 256 + (n >> 4)) * 1024 + (n & 15);  // + ch*16
#else
  const size_t vidx = (((size_t)b * 128 + (n >> 5)) * 4 + ((n >> 3) & 3)) * 512 + (n & 7);  // + ch*8
#endif
#pragma unroll
  for (int j = 0; j < 10; j++) {
    int ch = cb + j;
    if (ch < 8) {
      fh[pg * 8 + ch] = (_Float16)acc[j];
    } else if (ch < 16) {
      gh[pg * 8 + (ch - 8)] = (_Float16)acc[j];
    } else {
      __hip_bfloat16 hv = __float2bfloat16(acc[j]);
#if USE_K16
      vT[vidx + (size_t)(ch - 16) * 16] = *(unsigned short*)&hv;
#else
      vT[vidx + (size_t)(ch - 16) * 8] = *(unsigned short*)&hv;
#endif
    }
  }
}

// ---------------------------------------------------------------------------
// Kernel 2 (v7): flash attention, no-max softmax via exp2 (g prescaled).
// 1024 blocks x 512 thr (8 waves); wave w covers keys [w*512, w*512+512).
// K16 scores (d=8 lives in quads 0-1); P@V via 16x16x16 bf16 with V^T as
// A-operand (S^T C-layout == K16 B-layout: zero cross-lane moves).
// Denominator: ones-row MFMA accumulates sum_k P[k][q] on the correct lane.
// Independent acc chains for tile0/tile1; merged once after the loop.
// ---------------------------------------------------------------------------
__device__ __forceinline__ unsigned pack_bf16_2(float lo, float hi) {
  float2 f2; f2.x = lo; f2.y = hi;
  __hip_bfloat162 h2 = __float22bfloat162_rn(f2);
  return *reinterpret_cast<unsigned*>(&h2);
}

__global__ __launch_bounds__(512, 6) void attn_kernel(
    const _Float16* __restrict__ fh,        // [B][N][8] f16
    const _Float16* __restrict__ gh,        // [B][N][8] f16 (prescaled by log2e)
    const unsigned short* __restrict__ vT,  // tiled, see prep
    float* __restrict__ out)                // [B][N][64] f32
{
  const int N    = 4096;
  const int lane = threadIdx.x & 63;
  const int w    = threadIdx.x >> 6;       // 0..7
  const int quad = lane >> 4;
  const int l15  = lane & 15;

  __shared__ float red[7][64][17];  // waves 1-7: 16 acc + 1 l per lane

  const int xcd = blockIdx.x & 7;
  const int b   = xcd >> 1;
  const int sub = ((blockIdx.x >> 3) << 1) + (xcd & 1);  // 0..255 query tile
  const int q0  = sub * 16;
  const int kbase = w * 512;

  const _Float16* fbase = fh + (size_t)b * N * 8;
  const _Float16* gbase = gh + (size_t)b * N * 8;

  const f32x4 zc = {0.f, 0.f, 0.f, 0.f};
  f32x4 acc[4] = {zc, zc, zc, zc};
  float lv;

#if USE_K16
  // K16 g B-frag: B[k=d=quad*4+j][n=q=l15]; d<8 -> quads 0,1 only
  half4_t gfrag = {};
  if (quad < 2) gfrag = *(const half4_t*)(gbase + (size_t)(q0 + l15) * 8 + quad * 4);

  const short* vbat = (const short*)vT + (size_t)b * 262144 + (l15 << 4) + (quad << 2);

  f32x4 acc1[4] = {zc, zc, zc, zc};
  f32x4 acc4a = zc, acc4b = zc;
  short4_t ones;
  ones[0] = ones[1] = ones[2] = ones[3] = (short)0x3F80;  // bf16 1.0

#pragma unroll 4
  for (int cc = 0; cc < 16; cc++) {
    const int k0 = kbase + cc * 32;

    // scores S^T[key][q] via K16 f16 MFMA; f A-frag: A[key=l15][d=quad*4+j]
    half4_t f0 = {}, f1 = {};
    if (quad < 2) {
      f0 = *(const half4_t*)(fbase + (size_t)(k0 + l15) * 8 + quad * 4);
      f1 = *(const half4_t*)(fbase + (size_t)(k0 + 16 + l15) * 8 + quad * 4);
    }
    f32x4 s0 = __builtin_amdgcn_mfma_f32_16x16x16f16(f0, gfrag, zc, 0, 0, 0);
    f32x4 s1 = __builtin_amdgcn_mfma_f32_16x16x16f16(f1, gfrag, zc, 0, 0, 0);
    // lane: S^T[key = k0 + 16t + quad*4 + reg][q = l15] (already x log2e)

    float p00 = EXP2(s0[0]), p01 = EXP2(s0[1]), p02 = EXP2(s0[2]), p03 = EXP2(s0[3]);
    float p10 = EXP2(s1[0]), p11 = EXP2(s1[1]), p12 = EXP2(s1[2]), p13 = EXP2(s1[3]);

    union { unsigned u[2]; short4_t v; } b0u, b1u;
    b0u.u[0] = pack_bf16_2(p00, p01); b0u.u[1] = pack_bf16_2(p02, p03);
    b1u.u[0] = pack_bf16_2(p10, p11); b1u.u[1] = pack_bf16_2(p12, p13);
    // b0u.v / b1u.v are exactly the K16 B-frags B[k=quad*4+j][q=l15]

    // denominator: ones-row MFMA -> every lane gets sum_k p[k][q=l15]
    acc4a = __builtin_amdgcn_mfma_f32_16x16x16bf16_1k(ones, b0u.v, acc4a, 0, 0, 0);
    acc4b = __builtin_amdgcn_mfma_f32_16x16x16bf16_1k(ones, b1u.v, acc4b, 0, 0, 0);

    // P@V: V^T A-frags, 8B contiguous; all imm offsets within one 4KB block
    const short* vk = vbat + ((size_t)(k0 >> 4) << 10);
#pragma unroll
    for (int ct = 0; ct < 4; ct++) {
      short4_t va0 = *(const short4_t*)(vk + ct * 256);
      short4_t va1 = *(const short4_t*)(vk + 1024 + ct * 256);
      acc[ct]  = __builtin_amdgcn_mfma_f32_16x16x16bf16_1k(va0, b0u.v, acc[ct], 0, 0, 0);
      acc1[ct] = __builtin_amdgcn_mfma_f32_16x16x16bf16_1k(va1, b1u.v, acc1[ct], 0, 0, 0);
    }
  }
#pragma unroll
  for (int ct = 0; ct < 4; ct++) acc[ct] += acc1[ct];
  lv = acc4a[0] + acc4b[0];
#else
  // ---- fallback: R5 shuffle-based path (old vT frag tiling), exp2 variant ----
  half8_t gfrag8 = {};
  if (quad == 0) gfrag8 = *(const half8_t*)(gbase + (size_t)(q0 + l15) * 8);
  const short* vbat = (const short*)vT + (size_t)b * 262144 + (quad << 9) + (l15 << 3);
  const int  srcA = ((quad & 1) << 5) + l15;
  const int  srcB = srcA + 16;
  const bool hi   = (quad >= 2);
  float lpart = 0.f;

#pragma unroll 8
  for (int cc = 0; cc < 16; cc++) {
    const int k0 = kbase + cc * 32;
    half8_t f0 = {}, f1 = {};
    if (quad == 0) {
      f0 = *(const half8_t*)(fbase + (size_t)(k0 + l15) * 8);
      f1 = *(const half8_t*)(fbase + (size_t)(k0 + 16 + l15) * 8);
    }
    f32x4 s0 = __builtin_amdgcn_mfma_f32_16x16x32_f16(f0, gfrag8, zc, 0, 0, 0);
    f32x4 s1 = __builtin_amdgcn_mfma_f32_16x16x32_f16(f1, gfrag8, zc, 0, 0, 0);

    float p00 = EXP2(s0[0]), p01 = EXP2(s0[1]), p02 = EXP2(s0[2]), p03 = EXP2(s0[3]);
    float p10 = EXP2(s1[0]), p11 = EXP2(s1[1]), p12 = EXP2(s1[2]), p13 = EXP2(s1[3]);
    lpart += (p00 + p01 + p02 + p03) + (p10 + p11 + p12 + p13);

    unsigned pk00 = pack_bf16_2(p00, p01), pk01 = pack_bf16_2(p02, p03);
    unsigned pk10 = pack_bf16_2(p10, p11), pk11 = pack_bf16_2(p12, p13);

    unsigned t0aA = __shfl((int)pk00, srcA), t0bA = __shfl((int)pk01, srcA);
    unsigned t1aA = __shfl((int)pk10, srcA), t1bA = __shfl((int)pk11, srcA);
    unsigned t0aB = __shfl((int)pk00, srcB), t0bB = __shfl((int)pk01, srcB);
    unsigned t1aB = __shfl((int)pk10, srcB), t1bB = __shfl((int)pk11, srcB);
    union { unsigned u[4]; short8_t v; } au;
    au.u[0] = hi ? t1aA : t0aA;
    au.u[1] = hi ? t1bA : t0bA;
    au.u[2] = hi ? t1aB : t0aB;
    au.u[3] = hi ? t1bB : t0bB;
    short8_t afrag = au.v;

    const short* vk = vbat + ((size_t)(k0 >> 5) << 11);
    short8_t b0 = *(const short8_t*)(vk);
    short8_t b1 = *(const short8_t*)(vk + 128);
    short8_t b2 = *(const short8_t*)(vk + 256);
    short8_t b3 = *(const short8_t*)(vk + 384);
    acc[0] = __builtin_amdgcn_mfma_f32_16x16x32_bf16(afrag, b0, acc[0], 0, 0, 0);
    acc[1] = __builtin_amdgcn_mfma_f32_16x16x32_bf16(afrag, b1, acc[1], 0, 0, 0);
    acc[2] = __builtin_amdgcn_mfma_f32_16x16x32_bf16(afrag, b2, acc[2], 0, 0, 0);
    acc[3] = __builtin_amdgcn_mfma_f32_16x16x32_bf16(afrag, b3, acc[3], 0, 0, 0);
  }
  lv = lpart;
  lv += __shfl_xor(lv, 16);
  lv += __shfl_xor(lv, 32);
#endif

  // cross-wave combine
  if (w > 0) {
    float* p = &red[w - 1][lane][0];
#pragma unroll
    for (int ct = 0; ct < 4; ct++)
#pragma unroll
      for (int reg = 0; reg < 4; reg++) p[ct * 4 + reg] = acc[ct][reg];
    p[16] = lv;
  }
  __syncthreads();
  if (w == 0) {
#pragma unroll
    for (int ww = 0; ww < 7; ww++) {
      const float* p = &red[ww][lane][0];
#pragma unroll
      for (int ct = 0; ct < 4; ct++)
#pragma unroll
        for (int reg = 0; reg < 4; reg++) acc[ct][reg] += p[ct * 4 + reg];
      lv += p[16];
    }
#if USE_K16
    const float inv = 1.0f / lv;                   // this lane's q = l15
    float* ob = out + ((size_t)b * N + q0 + l15) * 64 + (quad << 2);
#pragma unroll
    for (int ct = 0; ct < 4; ct++) {
      f32x4 r = acc[ct] * inv;
      *(f32x4*)(ob + ct * 16) = r;                 // ch = ct*16 + quad*4 + reg
    }
#else
    float inv[4];
#pragma unroll
    for (int reg = 0; reg < 4; reg++)
      inv[reg] = 1.0f / __shfl(lv, quad * 4 + reg);
    float* ob = out + ((size_t)b * N + q0) * 64 + l15;
#pragma unroll
    for (int reg = 0; reg < 4; reg++)
#pragma unroll
      for (int ct = 0; ct < 4; ct++)
        ob[(quad * 4 + reg) * 64 + ct * 16] = acc[ct][reg] * inv[reg];
#endif
  }
}

// ---------------------------------------------------------------------------
extern "C" void kernel_launch(void* const* d_in, const int* in_sizes, int n_in,
                              void* d_out, int out_size, void* d_ws, size_t ws_size,
                              hipStream_t stream) {
  const float* x  = (const float*)d_in[0];
  const float* Wf = (const float*)d_in[1];
  const float* bf = (const float*)d_in[2];
  const float* Wg = (const float*)d_in[3];
  const float* bg = (const float*)d_in[4];
  const float* Wh = (const float*)d_in[5];
  const float* bh = (const float*)d_in[6];
  float* out = (float*)d_out;

  char* ws = (char*)d_ws;
  _Float16* fh = (_Float16*)ws;                        // 4*4096*8*2  = 256 KB
  _Float16* gh = (_Float16*)(ws + 262144);             // 256 KB
  unsigned short* vT = (unsigned short*)(ws + 524288); // 4*64*4096*2 = 2 MB

  prep_kernel<<<512, 256, 0, stream>>>(x, Wf, bf, Wg, bg, Wh, bh, fh, gh, vT);
  attn_kernel<<<1024, 512, 0, stream>>>(fh, gh, vT, out);
}

// Round 8
// 112.325 us; speedup vs baseline: 1.1135x; 1.1135x over previous
//
#include <hip/hip_runtime.h>
#include <hip/hip_bf16.h>
#include <hip/hip_fp16.h>

typedef _Float16 half8_t  __attribute__((ext_vector_type(8)));
typedef short    short8_t __attribute__((ext_vector_type(8)));
typedef float    f32x4    __attribute__((ext_vector_type(4)));

#define LOG2E 1.44269504088896f

// ---------------------------------------------------------------------------
// Kernel 1 (v6): f = x@Wf+bf (f16), g = (x@Wg+bg)*log2e (f16; attn uses raw
// v_exp_f32), vT2 = x@Wh+bh (bf16) in R5's MFMA-B-fragment tiling:
//   vT2[b][k>>5][(k>>3)&3][ch][k&7]  (per batch 262144 shorts)
// 512 blocks x 256 thr; block = 32 positions; thread = 10 of 80 concat chans.
// ---------------------------------------------------------------------------
__global__ __launch_bounds__(256) void prep_kernel(
    const float* __restrict__ x,
    const float* __restrict__ Wf, const float* __restrict__ bf,
    const float* __restrict__ Wg, const float* __restrict__ bg,
    const float* __restrict__ Wh, const float* __restrict__ bh,
    _Float16* __restrict__ fh, _Float16* __restrict__ gh,
    unsigned short* __restrict__ vT)
{
  __shared__ float XsT[64 * 33];
  __shared__ float Wall[64 * 80];
  __shared__ float ball[80];
  const int t  = threadIdx.x;
  const int p0 = blockIdx.x * 32;

  for (int i = t; i < 512; i += 256) {
    Wall[(i >> 3) * 80 + (i & 7)]     = Wf[i];
    Wall[(i >> 3) * 80 + 8 + (i & 7)] = Wg[i] * LOG2E;
  }
  for (int i = t; i < 4096; i += 256)
    Wall[(i >> 6) * 80 + 16 + (i & 63)] = Wh[i];
  if (t < 80) ball[t] = (t < 8) ? bf[t] : (t < 16) ? bg[t - 8] * LOG2E : bh[t - 16];

  const float4* xs = (const float4*)(x + (size_t)p0 * 64);
#pragma unroll
  for (int i = 0; i < 2; i++) {
    int idx = t + i * 256;
    int row = idx >> 4, c4 = idx & 15;
    float4 v = xs[idx];
    XsT[(c4 * 4 + 0) * 33 + row] = v.x;
    XsT[(c4 * 4 + 1) * 33 + row] = v.y;
    XsT[(c4 * 4 + 2) * 33 + row] = v.z;
    XsT[(c4 * 4 + 3) * 33 + row] = v.w;
  }
  __syncthreads();

  const int pos = t & 31;
  const int g   = t >> 5;
  const int cb  = g * 10;

  float acc[10];
#pragma unroll
  for (int j = 0; j < 10; j++) acc[j] = ball[cb + j];

  for (int c = 0; c < 64; c++) {
    float xv = XsT[c * 33 + pos];
    const float2* wr = (const float2*)&Wall[c * 80 + cb];
#pragma unroll
    for (int k = 0; k < 5; k++) {
      float2 w2 = wr[k];
      acc[2 * k]     += xv * w2.x;
      acc[2 * k + 1] += xv * w2.y;
    }
  }

  const size_t pg = (size_t)p0 + pos;
  const int b = (int)(pg >> 12);
  const int n = (int)(pg & 4095);
  const size_t vidx = (((size_t)b * 128 + (n >> 5)) * 4 + ((n >> 3) & 3)) * 512 + (n & 7);
#pragma unroll
  for (int j = 0; j < 10; j++) {
    int ch = cb + j;
    if (ch < 8) {
      fh[pg * 8 + ch] = (_Float16)acc[j];
    } else if (ch < 16) {
      gh[pg * 8 + (ch - 8)] = (_Float16)acc[j];
    } else {
      __hip_bfloat16 hv = __float2bfloat16(acc[j]);
      vT[vidx + (size_t)(ch - 16) * 8] = *(unsigned short*)&hv;
    }
  }
}

// ---------------------------------------------------------------------------
// Kernel 2 (v8): R5 skeleton + 32 queries/block + exp2.
// 512 blocks x 512 thr (8 waves). Block = one (batch, 32-query group) = two
// 16-q tiles A/B sharing every f-load and vT fragment-load (halves L2
// traffic vs R5, doubles per-wave ILP). Wave w covers keys [w*512, +512).
// K32 f16 scores (quad-0 f loads), shuffle C->A transform, K32 bf16 PV.
// LDS combine buffer reused across the two q-tiles (3 barriers).
// ---------------------------------------------------------------------------
__device__ __forceinline__ unsigned pack_bf16_2(float lo, float hi) {
  float2 f2; f2.x = lo; f2.y = hi;
  __hip_bfloat162 h2 = __float22bfloat162_rn(f2);
  return *reinterpret_cast<unsigned*>(&h2);
}

__global__ __launch_bounds__(512, 4) void attn_kernel(
    const _Float16* __restrict__ fh,        // [B][N][8] f16
    const _Float16* __restrict__ gh,        // [B][N][8] f16 (x log2e)
    const unsigned short* __restrict__ vT,  // frag-tiled, see prep
    float* __restrict__ out)                // [B][N][64] f32
{
  const int N    = 4096;
  const int lane = threadIdx.x & 63;
  const int w    = threadIdx.x >> 6;       // 0..7
  const int quad = lane >> 4;
  const int l15  = lane & 15;

  __shared__ float red[7][64][17];  // reused for q-tile A then B

  const int xcd = blockIdx.x & 7;
  const int b   = xcd >> 1;
  const int sub = ((blockIdx.x >> 3) << 1) + (xcd & 1);  // 0..127
  const int qA  = sub * 32;        // q-tile A rows
  const int qB  = qA + 16;         // q-tile B rows
  const int kbase = w * 512;

  const _Float16* fbase = fh + (size_t)b * N * 8;
  const _Float16* gbase = gh + (size_t)b * N * 8;
  const short*    vbat  = (const short*)vT + (size_t)b * 262144 + (quad << 9) + (l15 << 3);

  // G B-frags for both q-tiles: B[k=quad*8+j][n=q=l15]; quad 0 carries k<8
  half8_t gfragA = {}, gfragB = {};
  if (quad == 0) {
    gfragA = *(const half8_t*)(gbase + (size_t)(qA + l15) * 8);
    gfragB = *(const half8_t*)(gbase + (size_t)(qB + l15) * 8);
  }

  const f32x4 zc = {0.f, 0.f, 0.f, 0.f};
  f32x4 accA[4] = {zc, zc, zc, zc};
  f32x4 accB[4] = {zc, zc, zc, zc};
  float lpartA = 0.f, lpartB = 0.f;

  const int  srcA = ((quad & 1) << 5) + l15;
  const int  srcB = srcA + 16;
  const bool hi   = (quad >= 2);

#pragma unroll 4
  for (int cc = 0; cc < 16; cc++) {
    const int k0 = kbase + cc * 32;

    // ---- shared f loads (two 16-key tiles), masked to quad 0
    half8_t f0 = {}, f1 = {};
    if (quad == 0) {
      f0 = *(const half8_t*)(fbase + (size_t)(k0 + l15) * 8);
      f1 = *(const half8_t*)(fbase + (size_t)(k0 + 16 + l15) * 8);
    }
    // ---- shared vT fragment loads (one contiguous 4KB block)
    const short* vk = vbat + ((size_t)(k0 >> 5) << 11);
    short8_t v0 = *(const short8_t*)(vk);
    short8_t v1 = *(const short8_t*)(vk + 128);
    short8_t v2 = *(const short8_t*)(vk + 256);
    short8_t v3 = *(const short8_t*)(vk + 384);

    // ---- scores for both q-tiles
    f32x4 s0a = __builtin_amdgcn_mfma_f32_16x16x32_f16(f0, gfragA, zc, 0, 0, 0);
    f32x4 s1a = __builtin_amdgcn_mfma_f32_16x16x32_f16(f1, gfragA, zc, 0, 0, 0);
    f32x4 s0b = __builtin_amdgcn_mfma_f32_16x16x32_f16(f0, gfragB, zc, 0, 0, 0);
    f32x4 s1b = __builtin_amdgcn_mfma_f32_16x16x32_f16(f1, gfragB, zc, 0, 0, 0);

    // ---- exp2 (g prescaled by log2e)
    float pa00 = __builtin_amdgcn_exp2f(s0a[0]), pa01 = __builtin_amdgcn_exp2f(s0a[1]);
    float pa02 = __builtin_amdgcn_exp2f(s0a[2]), pa03 = __builtin_amdgcn_exp2f(s0a[3]);
    float pa10 = __builtin_amdgcn_exp2f(s1a[0]), pa11 = __builtin_amdgcn_exp2f(s1a[1]);
    float pa12 = __builtin_amdgcn_exp2f(s1a[2]), pa13 = __builtin_amdgcn_exp2f(s1a[3]);
    float pb00 = __builtin_amdgcn_exp2f(s0b[0]), pb01 = __builtin_amdgcn_exp2f(s0b[1]);
    float pb02 = __builtin_amdgcn_exp2f(s0b[2]), pb03 = __builtin_amdgcn_exp2f(s0b[3]);
    float pb10 = __builtin_amdgcn_exp2f(s1b[0]), pb11 = __builtin_amdgcn_exp2f(s1b[1]);
    float pb12 = __builtin_amdgcn_exp2f(s1b[2]), pb13 = __builtin_amdgcn_exp2f(s1b[3]);
    lpartA += (pa00 + pa01 + pa02 + pa03) + (pa10 + pa11 + pa12 + pa13);
    lpartB += (pb00 + pb01 + pb02 + pb03) + (pb10 + pb11 + pb12 + pb13);

    // ---- pack + C->A shuffle transform, q-tile A
    {
      unsigned pk00 = pack_bf16_2(pa00, pa01), pk01 = pack_bf16_2(pa02, pa03);
      unsigned pk10 = pack_bf16_2(pa10, pa11), pk11 = pack_bf16_2(pa12, pa13);
      unsigned t0aA = __shfl((int)pk00, srcA), t0bA = __shfl((int)pk01, srcA);
      unsigned t1aA = __shfl((int)pk10, srcA), t1bA = __shfl((int)pk11, srcA);
      unsigned t0aB = __shfl((int)pk00, srcB), t0bB = __shfl((int)pk01, srcB);
      unsigned t1aB = __shfl((int)pk10, srcB), t1bB = __shfl((int)pk11, srcB);
      union { unsigned u[4]; short8_t v; } au;
      au.u[0] = hi ? t1aA : t0aA;
      au.u[1] = hi ? t1bA : t0bA;
      au.u[2] = hi ? t1aB : t0aB;
      au.u[3] = hi ? t1bB : t0bB;
      accA[0] = __builtin_amdgcn_mfma_f32_16x16x32_bf16(au.v, v0, accA[0], 0, 0, 0);
      accA[1] = __builtin_amdgcn_mfma_f32_16x16x32_bf16(au.v, v1, accA[1], 0, 0, 0);
      accA[2] = __builtin_amdgcn_mfma_f32_16x16x32_bf16(au.v, v2, accA[2], 0, 0, 0);
      accA[3] = __builtin_amdgcn_mfma_f32_16x16x32_bf16(au.v, v3, accA[3], 0, 0, 0);
    }
    // ---- pack + transform, q-tile B (reuses the same vT frags)
    {
      unsigned pk00 = pack_bf16_2(pb00, pb01), pk01 = pack_bf16_2(pb02, pb03);
      unsigned pk10 = pack_bf16_2(pb10, pb11), pk11 = pack_bf16_2(pb12, pb13);
      unsigned t0aA = __shfl((int)pk00, srcA), t0bA = __shfl((int)pk01, srcA);
      unsigned t1aA = __shfl((int)pk10, srcA), t1bA = __shfl((int)pk11, srcA);
      unsigned t0aB = __shfl((int)pk00, srcB), t0bB = __shfl((int)pk01, srcB);
      unsigned t1aB = __shfl((int)pk10, srcB), t1bB = __shfl((int)pk11, srcB);
      union { unsigned u[4]; short8_t v; } au;
      au.u[0] = hi ? t1aA : t0aA;
      au.u[1] = hi ? t1bA : t0bA;
      au.u[2] = hi ? t1aB : t0aB;
      au.u[3] = hi ? t1bB : t0bB;
      accB[0] = __builtin_amdgcn_mfma_f32_16x16x32_bf16(au.v, v0, accB[0], 0, 0, 0);
      accB[1] = __builtin_amdgcn_mfma_f32_16x16x32_bf16(au.v, v1, accB[1], 0, 0, 0);
      accB[2] = __builtin_amdgcn_mfma_f32_16x16x32_bf16(au.v, v2, accB[2], 0, 0, 0);
      accB[3] = __builtin_amdgcn_mfma_f32_16x16x32_bf16(au.v, v3, accB[3], 0, 0, 0);
    }
  }

  // per-wave l for each q-tile (all quads summed -> every lane holds q=l15)
  float lvA = lpartA;
  lvA += __shfl_xor(lvA, 16);
  lvA += __shfl_xor(lvA, 32);
  float lvB = lpartB;
  lvB += __shfl_xor(lvB, 16);
  lvB += __shfl_xor(lvB, 32);

  // ---- combine phase A ----
  if (w > 0) {
    float* p = &red[w - 1][lane][0];
#pragma unroll
    for (int ct = 0; ct < 4; ct++)
#pragma unroll
      for (int reg = 0; reg < 4; reg++) p[ct * 4 + reg] = accA[ct][reg];
    p[16] = lvA;
  }
  __syncthreads();
  if (w == 0) {
#pragma unroll
    for (int ww = 0; ww < 7; ww++) {
      const float* p = &red[ww][lane][0];
#pragma unroll
      for (int ct = 0; ct < 4; ct++)
#pragma unroll
        for (int reg = 0; reg < 4; reg++) accA[ct][reg] += p[ct * 4 + reg];
      lvA += p[16];
    }
    float inv[4];
#pragma unroll
    for (int reg = 0; reg < 4; reg++)
      inv[reg] = 1.0f / __shfl(lvA, quad * 4 + reg);
    float* ob = out + ((size_t)b * N + qA) * 64 + l15;
#pragma unroll
    for (int reg = 0; reg < 4; reg++)
#pragma unroll
      for (int ct = 0; ct < 4; ct++)
        ob[(quad * 4 + reg) * 64 + ct * 16] = accA[ct][reg] * inv[reg];
  }
  __syncthreads();   // w0 done reading phase A before overwrite

  // ---- combine phase B ----
  if (w > 0) {
    float* p = &red[w - 1][lane][0];
#pragma unroll
    for (int ct = 0; ct < 4; ct++)
#pragma unroll
      for (int reg = 0; reg < 4; reg++) p[ct * 4 + reg] = accB[ct][reg];
    p[16] = lvB;
  }
  __syncthreads();
  if (w == 0) {
#pragma unroll
    for (int ww = 0; ww < 7; ww++) {
      const float* p = &red[ww][lane][0];
#pragma unroll
      for (int ct = 0; ct < 4; ct++)
#pragma unroll
        for (int reg = 0; reg < 4; reg++) accB[ct][reg] += p[ct * 4 + reg];
      lvB += p[16];
    }
    float inv[4];
#pragma unroll
    for (int reg = 0; reg < 4; reg++)
      inv[reg] = 1.0f / __shfl(lvB, quad * 4 + reg);
    float* ob = out + ((size_t)b * N + qB) * 64 + l15;
#pragma unroll
    for (int reg = 0; reg < 4; reg++)
#pragma unroll
      for (int ct = 0; ct < 4; ct++)
        ob[(quad * 4 + reg) * 64 + ct * 16] = accB[ct][reg] * inv[reg];
  }
}

// ---------------------------------------------------------------------------
extern "C" void kernel_launch(void* const* d_in, const int* in_sizes, int n_in,
                              void* d_out, int out_size, void* d_ws, size_t ws_size,
                              hipStream_t stream) {
  const float* x  = (const float*)d_in[0];
  const float* Wf = (const float*)d_in[1];
  const float* bf = (const float*)d_in[2];
  const float* Wg = (const float*)d_in[3];
  const float* bg = (const float*)d_in[4];
  const float* Wh = (const float*)d_in[5];
  const float* bh = (const float*)d_in[6];
  float* out = (float*)d_out;

  char* ws = (char*)d_ws;
  _Float16* fh = (_Float16*)ws;                        // 256 KB
  _Float16* gh = (_Float16*)(ws + 262144);             // 256 KB
  unsigned short* vT = (unsigned short*)(ws + 524288); // 2 MB

  prep_kernel<<<512, 256, 0, stream>>>(x, Wf, bf, Wg, bg, Wh, bh, fh, gh, vT);
  attn_kernel<<<512, 512, 0, stream>>>(fh, gh, vT, out);
}

// Round 9
// 105.542 us; speedup vs baseline: 1.1851x; 1.0643x over previous
//
#include <hip/hip_runtime.h>
#include <hip/hip_bf16.h>
#include <hip/hip_fp16.h>

typedef _Float16 half8_t  __attribute__((ext_vector_type(8)));
typedef short    short8_t __attribute__((ext_vector_type(8)));
typedef float    f32x4    __attribute__((ext_vector_type(4)));

#define LOG2E 1.44269504088896f

// ---------------------------------------------------------------------------
// Kernel 1 (v6): f = x@Wf+bf (f16), g = (x@Wg+bg)*log2e (f16; attn uses raw
// v_exp_f32 on base-2 logits), vT2 = x@Wh+bh (bf16) in MFMA-B-frag tiling:
//   vT2[b][k>>5][(k>>3)&3][ch][k&7]  (per batch 262144 shorts)
// 512 blocks x 256 thr; block = 32 positions; thread = 10 of 80 concat chans.
// ---------------------------------------------------------------------------
__global__ __launch_bounds__(256) void prep_kernel(
    const float* __restrict__ x,
    const float* __restrict__ Wf, const float* __restrict__ bf,
    const float* __restrict__ Wg, const float* __restrict__ bg,
    const float* __restrict__ Wh, const float* __restrict__ bh,
    _Float16* __restrict__ fh, _Float16* __restrict__ gh,
    unsigned short* __restrict__ vT)
{
  __shared__ float XsT[64 * 33];
  __shared__ float Wall[64 * 80];
  __shared__ float ball[80];
  const int t  = threadIdx.x;
  const int p0 = blockIdx.x * 32;

  for (int i = t; i < 512; i += 256) {
    Wall[(i >> 3) * 80 + (i & 7)]     = Wf[i];
    Wall[(i >> 3) * 80 + 8 + (i & 7)] = Wg[i] * LOG2E;
  }
  for (int i = t; i < 4096; i += 256)
    Wall[(i >> 6) * 80 + 16 + (i & 63)] = Wh[i];
  if (t < 80) ball[t] = (t < 8) ? bf[t] : (t < 16) ? bg[t - 8] * LOG2E : bh[t - 16];

  const float4* xs = (const float4*)(x + (size_t)p0 * 64);
#pragma unroll
  for (int i = 0; i < 2; i++) {
    int idx = t + i * 256;
    int row = idx >> 4, c4 = idx & 15;
    float4 v = xs[idx];
    XsT[(c4 * 4 + 0) * 33 + row] = v.x;
    XsT[(c4 * 4 + 1) * 33 + row] = v.y;
    XsT[(c4 * 4 + 2) * 33 + row] = v.z;
    XsT[(c4 * 4 + 3) * 33 + row] = v.w;
  }
  __syncthreads();

  const int pos = t & 31;
  const int g   = t >> 5;
  const int cb  = g * 10;

  float acc[10];
#pragma unroll
  for (int j = 0; j < 10; j++) acc[j] = ball[cb + j];

  for (int c = 0; c < 64; c++) {
    float xv = XsT[c * 33 + pos];
    const float2* wr = (const float2*)&Wall[c * 80 + cb];
#pragma unroll
    for (int k = 0; k < 5; k++) {
      float2 w2 = wr[k];
      acc[2 * k]     += xv * w2.x;
      acc[2 * k + 1] += xv * w2.y;
    }
  }

  const size_t pg = (size_t)p0 + pos;
  const int b = (int)(pg >> 12);
  const int n = (int)(pg & 4095);
  const size_t vidx = (((size_t)b * 128 + (n >> 5)) * 4 + ((n >> 3) & 3)) * 512 + (n & 7);
#pragma unroll
  for (int j = 0; j < 10; j++) {
    int ch = cb + j;
    if (ch < 8) {
      fh[pg * 8 + ch] = (_Float16)acc[j];
    } else if (ch < 16) {
      gh[pg * 8 + (ch - 8)] = (_Float16)acc[j];
    } else {
      __hip_bfloat16 hv = __float2bfloat16(acc[j]);
      vT[vidx + (size_t)(ch - 16) * 8] = *(unsigned short*)&hv;
    }
  }
}

// ---------------------------------------------------------------------------
// Kernel 2 (v9): R5 skeleton + exp2 + ones-column-MFMA denominator.
// 1024 blocks x 512 thr (8 waves); block = (batch, 16-q tile); wave w covers
// keys [w*512, +512). K32 f16 scores, shuffle C->A transform, K32 bf16 PV.
// Denominator: 5th PV MFMA vs constant-1.0 B-frag -> acc4[reg] = l for
// q = quad*4+reg (C-layout) — no VALU adds, no end shuffles, shuffle-free
// epilogue divide. f0/f1 zero-init hoisted (non-quad0 lanes never written).
// ---------------------------------------------------------------------------
__device__ __forceinline__ unsigned pack_bf16_2(float lo, float hi) {
  float2 f2; f2.x = lo; f2.y = hi;
  __hip_bfloat162 h2 = __float22bfloat162_rn(f2);
  return *reinterpret_cast<unsigned*>(&h2);
}

__global__ __launch_bounds__(512, 4) void attn_kernel(
    const _Float16* __restrict__ fh,        // [B][N][8] f16
    const _Float16* __restrict__ gh,        // [B][N][8] f16 (x log2e)
    const unsigned short* __restrict__ vT,  // frag-tiled, see prep
    float* __restrict__ out)                // [B][N][64] f32
{
  const int N    = 4096;
  const int lane = threadIdx.x & 63;
  const int w    = threadIdx.x >> 6;       // 0..7
  const int quad = lane >> 4;
  const int l15  = lane & 15;

  __shared__ float red[7][64][21];  // waves 1-7: 16 acc + 4 l per lane (pad 21)

  const int xcd = blockIdx.x & 7;
  const int b   = xcd >> 1;
  const int sub = ((blockIdx.x >> 3) << 1) + (xcd & 1);  // 0..255 q tile
  const int q0  = sub * 16;
  const int kbase = w * 512;

  const _Float16* fbase = fh + (size_t)b * N * 8;
  const _Float16* gbase = gh + (size_t)b * N * 8;
  const short*    vbat  = (const short*)vT + (size_t)b * 262144 + (quad << 9) + (l15 << 3);

  // G B-frag: B[k=quad*8+j][n=q=l15]; only quad 0 carries real k (DK=8)
  half8_t gfrag = {};
  if (quad == 0) gfrag = *(const half8_t*)(gbase + (size_t)(q0 + l15) * 8);

  const f32x4 zc = {0.f, 0.f, 0.f, 0.f};
  f32x4 acc[4] = {zc, zc, zc, zc};   // D[q=quad*4+reg][chan=ct*16+l15]
  f32x4 acc4   = zc;                 // D[q=quad*4+reg][*] = sum_k P  (denominator)

  short8_t ones8;
#pragma unroll
  for (int i = 0; i < 8; i++) ones8[i] = (short)0x3F80;  // bf16 1.0

  const int  srcA = ((quad & 1) << 5) + l15;
  const int  srcB = srcA + 16;
  const bool hi   = (quad >= 2);

  half8_t f0 = {}, f1 = {};          // zero-init ONCE; non-quad0 lanes stay 0

#pragma unroll 8
  for (int cc = 0; cc < 16; cc++) {
    const int k0 = kbase + cc * 32;

    if (quad == 0) {
      f0 = *(const half8_t*)(fbase + (size_t)(k0 + l15) * 8);
      f1 = *(const half8_t*)(fbase + (size_t)(k0 + 16 + l15) * 8);
    }
    const short* vk = vbat + ((size_t)(k0 >> 5) << 11);
    short8_t v0 = *(const short8_t*)(vk);
    short8_t v1 = *(const short8_t*)(vk + 128);
    short8_t v2 = *(const short8_t*)(vk + 256);
    short8_t v3 = *(const short8_t*)(vk + 384);

    f32x4 s0 = __builtin_amdgcn_mfma_f32_16x16x32_f16(f0, gfrag, zc, 0, 0, 0);
    f32x4 s1 = __builtin_amdgcn_mfma_f32_16x16x32_f16(f1, gfrag, zc, 0, 0, 0);
    // lane: S^T[key = k0 + 16t + quad*4 + reg][q = l15], logits already x log2e

    float p00 = __builtin_amdgcn_exp2f(s0[0]), p01 = __builtin_amdgcn_exp2f(s0[1]);
    float p02 = __builtin_amdgcn_exp2f(s0[2]), p03 = __builtin_amdgcn_exp2f(s0[3]);
    float p10 = __builtin_amdgcn_exp2f(s1[0]), p11 = __builtin_amdgcn_exp2f(s1[1]);
    float p12 = __builtin_amdgcn_exp2f(s1[2]), p13 = __builtin_amdgcn_exp2f(s1[3]);

    unsigned pk00 = pack_bf16_2(p00, p01), pk01 = pack_bf16_2(p02, p03);
    unsigned pk10 = pack_bf16_2(p10, p11), pk11 = pack_bf16_2(p12, p13);

    // C-layout -> A-layout: lane (quad,l15) needs P[q=l15][kk=quad*8+j]
    unsigned t0aA = __shfl((int)pk00, srcA), t0bA = __shfl((int)pk01, srcA);
    unsigned t1aA = __shfl((int)pk10, srcA), t1bA = __shfl((int)pk11, srcA);
    unsigned t0aB = __shfl((int)pk00, srcB), t0bB = __shfl((int)pk01, srcB);
    unsigned t1aB = __shfl((int)pk10, srcB), t1bB = __shfl((int)pk11, srcB);
    union { unsigned u[4]; short8_t v; } au;
    au.u[0] = hi ? t1aA : t0aA;
    au.u[1] = hi ? t1bA : t0bA;
    au.u[2] = hi ? t1aB : t0aB;
    au.u[3] = hi ? t1bB : t0bB;
    short8_t afrag = au.v;

    acc[0] = __builtin_amdgcn_mfma_f32_16x16x32_bf16(afrag, v0, acc[0], 0, 0, 0);
    acc[1] = __builtin_amdgcn_mfma_f32_16x16x32_bf16(afrag, v1, acc[1], 0, 0, 0);
    acc[2] = __builtin_amdgcn_mfma_f32_16x16x32_bf16(afrag, v2, acc[2], 0, 0, 0);
    acc[3] = __builtin_amdgcn_mfma_f32_16x16x32_bf16(afrag, v3, acc[3], 0, 0, 0);
    acc4   = __builtin_amdgcn_mfma_f32_16x16x32_bf16(afrag, ones8, acc4, 0, 0, 0);
  }

  // cross-wave combine (acc + acc4)
  if (w > 0) {
    float* p = &red[w - 1][lane][0];
#pragma unroll
    for (int ct = 0; ct < 4; ct++)
#pragma unroll
      for (int reg = 0; reg < 4; reg++) p[ct * 4 + reg] = acc[ct][reg];
#pragma unroll
    for (int reg = 0; reg < 4; reg++) p[16 + reg] = acc4[reg];
  }
  __syncthreads();
  if (w == 0) {
#pragma unroll
    for (int ww = 0; ww < 7; ww++) {
      const float* p = &red[ww][lane][0];
#pragma unroll
      for (int ct = 0; ct < 4; ct++)
#pragma unroll
        for (int reg = 0; reg < 4; reg++) acc[ct][reg] += p[ct * 4 + reg];
#pragma unroll
      for (int reg = 0; reg < 4; reg++) acc4[reg] += p[16 + reg];
    }
    // denominator already in row-matched C-layout: no shuffles needed
    float inv[4];
#pragma unroll
    for (int reg = 0; reg < 4; reg++) inv[reg] = 1.0f / acc4[reg];

    float* ob = out + ((size_t)b * N + q0) * 64 + l15;
#pragma unroll
    for (int reg = 0; reg < 4; reg++)
#pragma unroll
      for (int ct = 0; ct < 4; ct++)
        ob[(quad * 4 + reg) * 64 + ct * 16] = acc[ct][reg] * inv[reg];
  }
}

// ---------------------------------------------------------------------------
extern "C" void kernel_launch(void* const* d_in, const int* in_sizes, int n_in,
                              void* d_out, int out_size, void* d_ws, size_t ws_size,
                              hipStream_t stream) {
  const float* x  = (const float*)d_in[0];
  const float* Wf = (const float*)d_in[1];
  const float* bf = (const float*)d_in[2];
  const float* Wg = (const float*)d_in[3];
  const float* bg = (const float*)d_in[4];
  const float* Wh = (const float*)d_in[5];
  const float* bh = (const float*)d_in[6];
  float* out = (float*)d_out;

  char* ws = (char*)d_ws;
  _Float16* fh = (_Float16*)ws;                        // 256 KB
  _Float16* gh = (_Float16*)(ws + 262144);             // 256 KB
  unsigned short* vT = (unsigned short*)(ws + 524288); // 2 MB

  prep_kernel<<<512, 256, 0, stream>>>(x, Wf, bf, Wg, bg, Wh, bh, fh, gh, vT);
  attn_kernel<<<1024, 512, 0, stream>>>(fh, gh, vT, out);
}